// Round 1
// baseline (1414.200 us; speedup 1.0000x reference)
//
#include <hip/hip_runtime.h>
#include <hip/hip_bf16.h>

// E71 Delta cell: T=2048, B=16, D=1024, N=128
// proj layout in ws: [t][b][512] f32, cols 0..127=k, 128..255=v, 256..383=q, 384..511=bx

#define T_STEPS 2048
#define NB 16
#define ND 128
#define KD 1024
#define PSTRIDE 512

typedef __attribute__((ext_vector_type(4))) float f32x4;
typedef __attribute__((ext_vector_type(8))) short short8v;

__device__ __forceinline__ unsigned short f2bf(float f) {
  union { float f; unsigned int u; } c; c.f = f;
  unsigned int u = c.u;
  unsigned int r = u + 0x7fffu + ((u >> 16) & 1u);   // round-to-nearest-even
  return (unsigned short)(r >> 16);
}

// ---------------------------------------------------------------------------
// Projection GEMM: C[m][n] = sum_k bf16(X[m][k]) * bf16(W_sel[n%128][k])
// M=32768, N=512 (4 col-tiles of 128, one per weight matrix), K=1024.
// 128x128 tile, BK=64, 4 waves, XOR-swizzled LDS (chunk ^= row&7) so frag
// ds_read_b128 at row-stride 128B doesn't 16-way bank-conflict (G4).
// ---------------------------------------------------------------------------
__global__ __launch_bounds__(256) void proj_gemm(
    const float* __restrict__ X,
    const float* __restrict__ Wk, const float* __restrict__ Wv,
    const float* __restrict__ Wq, const float* __restrict__ Wb,
    float* __restrict__ C)
{
  __shared__ unsigned short As[128 * 64];
  __shared__ unsigned short Bs[128 * 64];
  const int tid = threadIdx.x;
  const int bm = blockIdx.x;           // 0..255
  const int bn = blockIdx.y;           // 0..3 -> which weight matrix
  const float* W = (bn == 0) ? Wk : ((bn == 1) ? Wv : ((bn == 2) ? Wq : Wb));
  const int lane = tid & 63;
  const int wave = tid >> 6;
  const int wr = wave >> 1, wc = wave & 1;   // wave computes 64x64 sub-tile

  f32x4 acc[4][4];
#pragma unroll
  for (int i = 0; i < 4; i++)
#pragma unroll
    for (int j = 0; j < 4; j++) acc[i][j] = (f32x4){0.f, 0.f, 0.f, 0.f};

  for (int k0 = 0; k0 < KD; k0 += 64) {
    __syncthreads();                   // protect LDS vs previous iter's reads
    // stage: 128 rows x 64 cols each for A and B; thread does 4 chunks of 8
    // f32 -> 8 bf16 per matrix. Coalesced float4 reads; swizzled b128 writes.
#pragma unroll
    for (int c = 0; c < 4; c++) {
      const int g = tid + c * 256;     // 0..1023
      const int row = g >> 3;
      const int ch = g & 7;
      const int pos = ((ch ^ (row & 7)) * 8);
      {
        const float* ga = X + (size_t)(bm * 128 + row) * KD + k0 + ch * 8;
        float4 f0 = *(const float4*)(ga);
        float4 f1 = *(const float4*)(ga + 4);
        union { unsigned short u[8]; short8v v; } pk2;
        pk2.u[0] = f2bf(f0.x); pk2.u[1] = f2bf(f0.y);
        pk2.u[2] = f2bf(f0.z); pk2.u[3] = f2bf(f0.w);
        pk2.u[4] = f2bf(f1.x); pk2.u[5] = f2bf(f1.y);
        pk2.u[6] = f2bf(f1.z); pk2.u[7] = f2bf(f1.w);
        *reinterpret_cast<short8v*>(&As[row * 64 + pos]) = pk2.v;
      }
      {
        const float* gb = W + (size_t)row * KD + k0 + ch * 8;
        float4 f0 = *(const float4*)(gb);
        float4 f1 = *(const float4*)(gb + 4);
        union { unsigned short u[8]; short8v v; } pk2;
        pk2.u[0] = f2bf(f0.x); pk2.u[1] = f2bf(f0.y);
        pk2.u[2] = f2bf(f0.z); pk2.u[3] = f2bf(f0.w);
        pk2.u[4] = f2bf(f1.x); pk2.u[5] = f2bf(f1.y);
        pk2.u[6] = f2bf(f1.z); pk2.u[7] = f2bf(f1.w);
        *reinterpret_cast<short8v*>(&Bs[row * 64 + pos]) = pk2.v;
      }
    }
    __syncthreads();
    // compute: 2 k-slices of 32, 16 MFMAs each
#pragma unroll
    for (int kk = 0; kk < 2; kk++) {
      const int ch = kk * 4 + (lane >> 4);   // chunk of 8 k-elements
      short8v a[4], b[4];
#pragma unroll
      for (int i = 0; i < 4; i++) {
        const int ar = wr * 64 + i * 16 + (lane & 15);
        a[i] = *reinterpret_cast<const short8v*>(&As[ar * 64 + ((ch ^ (ar & 7)) * 8)]);
        const int br = wc * 64 + i * 16 + (lane & 15);
        b[i] = *reinterpret_cast<const short8v*>(&Bs[br * 64 + ((ch ^ (br & 7)) * 8)]);
      }
#pragma unroll
      for (int i = 0; i < 4; i++)
#pragma unroll
        for (int j = 0; j < 4; j++)
          acc[i][j] = __builtin_amdgcn_mfma_f32_16x16x32_bf16(a[i], b[j], acc[i][j], 0, 0, 0);
    }
  }
  // epilogue: C/D layout col=lane&15, row=(lane>>4)*4+r (m89-verified)
#pragma unroll
  for (int i = 0; i < 4; i++)
#pragma unroll
    for (int j = 0; j < 4; j++)
#pragma unroll
      for (int r = 0; r < 4; r++) {
        const int row = bm * 128 + wr * 64 + i * 16 + (lane >> 4) * 4 + r;
        const int col = bn * 128 + wc * 64 + j * 16 + (lane & 15);
        C[(size_t)row * PSTRIDE + col] = acc[i][j][r];
      }
}

// ---------------------------------------------------------------------------
// Sequential delta-rule scan. One wave per (batch, 8-row group):
// 256 single-wave blocks, zero barriers, zero LDS, S in registers.
// lane = rloc*8 + cblk: owns rows (wv*8+rloc), cols [cblk*16, cblk*16+16).
// Each 8-lane group (fixed rloc) holds a full 128-wide copy of k/q ->
// reductions are 3x shfl_xor (masks 1,2,4).
// ---------------------------------------------------------------------------
__device__ __forceinline__ float sum8(float v) {
  v += __shfl_xor(v, 1);
  v += __shfl_xor(v, 2);
  v += __shfl_xor(v, 4);
  return v;
}

__device__ __forceinline__ void load_step(const float* __restrict__ p, int cblk, int row,
                                          float4 k[4], float4 q[4], float& v, float& bx) {
  const float4* p4 = reinterpret_cast<const float4*>(p);
#pragma unroll
  for (int j = 0; j < 4; j++) k[j] = p4[cblk * 4 + j];          // k: cols c0..c0+15
#pragma unroll
  for (int j = 0; j < 4; j++) q[j] = p4[64 + cblk * 4 + j];     // q at float offset 256
  v = p[128 + row];
  bx = p[384 + row];
}

__device__ __forceinline__ float do_step(const float4 k[4], const float4 q[4],
                                         float v, float bx, float db, float bb,
                                         float S[16]) {
  float ssa[4], dka[4];
#pragma unroll
  for (int j = 0; j < 4; j++) {
    ssa[j] = k[j].x * k[j].x + k[j].y * k[j].y + k[j].z * k[j].z + k[j].w * k[j].w;
    dka[j] = S[4 * j + 0] * k[j].x + S[4 * j + 1] * k[j].y +
             S[4 * j + 2] * k[j].z + S[4 * j + 3] * k[j].w;
  }
  float ss = sum8((ssa[0] + ssa[1]) + (ssa[2] + ssa[3]));
  float dk = sum8((dka[0] + dka[1]) + (dka[2] + dka[3]));
  const float rn = 1.0f / (sqrtf(ss) + 1e-6f);      // 1/(||k||+eps)
  const float r = dk * rn;                           // retrieved[row]
  const float lg = fmaf(db, r, bx) + bb;
  const float beta = 1.0f / (1.0f + __expf(-lg));
  const float cr = beta * (v - r) * rn;              // folded: beta*(v-r), * rnorm
  float oda[4] = {0.f, 0.f, 0.f, 0.f};
#pragma unroll
  for (int j = 0; j < 4; j++) {
    S[4 * j + 0] = fmaf(cr, k[j].x, S[4 * j + 0]); oda[j] = fmaf(S[4 * j + 0], q[j].x, oda[j]);
    S[4 * j + 1] = fmaf(cr, k[j].y, S[4 * j + 1]); oda[j] = fmaf(S[4 * j + 1], q[j].y, oda[j]);
    S[4 * j + 2] = fmaf(cr, k[j].z, S[4 * j + 2]); oda[j] = fmaf(S[4 * j + 2], q[j].z, oda[j]);
    S[4 * j + 3] = fmaf(cr, k[j].w, S[4 * j + 3]); oda[j] = fmaf(S[4 * j + 3], q[j].w, oda[j]);
  }
  const float od = sum8((oda[0] + oda[1]) + (oda[2] + oda[3]));  // out = S@q
  const float sg = 1.0f / (1.0f + __expf(-od));
  return od * od * sg;                               // out * silu(out)
}

__global__ __launch_bounds__(64) void scan_kernel(
    const float* __restrict__ proj, const float* __restrict__ S_in,
    const float* __restrict__ d_beta, const float* __restrict__ b_beta,
    float* __restrict__ out, float* __restrict__ S_out)
{
  const int lane = threadIdx.x & 63;
  // batch = blockIdx & 15: batches b and b+8 share XCD b%8 (blocks congruent
  // mod 8) so each XCD's L2 holds only its 2 batches' proj slices.
  const int batch = blockIdx.x & 15;
  const int wv = blockIdx.x >> 4;      // 0..15 row-group
  const int rloc = lane >> 3;
  const int row = wv * 8 + rloc;
  const int cblk = lane & 7;
  const int c0 = cblk * 16;

  float S[16];
  {
    const float4* Sp4 = reinterpret_cast<const float4*>(
        S_in + ((size_t)batch * ND + row) * ND + c0);
#pragma unroll
    for (int j = 0; j < 4; j++) {
      float4 s4 = Sp4[j];
      S[4 * j + 0] = s4.x; S[4 * j + 1] = s4.y; S[4 * j + 2] = s4.z; S[4 * j + 3] = s4.w;
    }
  }
  const float db = d_beta[row];
  const float bb = b_beta[row];

  const float* p = proj + (size_t)batch * PSTRIDE;
  float* outp = out + (size_t)batch * ND + row;

  float4 ka[4], qa[4]; float va, bxa;
  float4 kb[4], qb[4]; float vb, bxb;
  load_step(p, cblk, row, ka, qa, va, bxa);        // t = 0

  for (int t = 0; t < T_STEPS; t += 2) {
    const float* p1 = p + NB * PSTRIDE;            // t+1 (always < T: t<=2046)
    load_step(p1, cblk, row, kb, qb, vb, bxb);     // prefetch overlaps compute
    float g0 = do_step(ka, qa, va, bxa, db, bb, S);
    if (cblk == 0) outp[0] = g0;
    outp += NB * ND;
    const float* p2 = (t + 2 < T_STEPS) ? p1 + NB * PSTRIDE : p1;  // clamp tail
    load_step(p2, cblk, row, ka, qa, va, bxa);
    float g1 = do_step(kb, qb, vb, bxb, db, bb, S);
    if (cblk == 0) outp[0] = g1;
    outp += NB * ND;
    p = p2;
  }
  {
    float4* So4 = reinterpret_cast<float4*>(
        S_out + ((size_t)batch * ND + row) * ND + c0);
#pragma unroll
    for (int j = 0; j < 4; j++) {
      float4 s4;
      s4.x = S[4 * j + 0]; s4.y = S[4 * j + 1]; s4.z = S[4 * j + 2]; s4.w = S[4 * j + 3];
      So4[j] = s4;
    }
  }
}

extern "C" void kernel_launch(void* const* d_in, const int* in_sizes, int n_in,
                              void* d_out, int out_size, void* d_ws, size_t ws_size,
                              hipStream_t stream) {
  const float* x  = (const float*)d_in[0];   // [2048][16][1024]
  const float* S0 = (const float*)d_in[1];   // [16][128][128]
  const float* Wk = (const float*)d_in[2];
  const float* Wv = (const float*)d_in[3];
  const float* Wq = (const float*)d_in[4];
  const float* Wb = (const float*)d_in[5];
  const float* db = (const float*)d_in[6];
  const float* bb = (const float*)d_in[7];
  float* out  = (float*)d_out;                           // [2048][16][128]
  float* Sout = out + (size_t)T_STEPS * NB * ND;         // [16][128][128]
  float* proj = (float*)d_ws;                            // [32768][512] = 64 MB

  dim3 ggrid(256, 4);
  proj_gemm<<<ggrid, 256, 0, stream>>>(x, Wk, Wv, Wq, Wb, proj);
  scan_kernel<<<256, 64, 0, stream>>>(proj, S0, db, bb, out, Sout);
}

// Round 2
// 951.692 us; speedup vs baseline: 1.4860x; 1.4860x over previous
//
#include <hip/hip_runtime.h>
#include <hip/hip_bf16.h>

// E71 Delta cell: T=2048, B=16, D=1024, N=128
// proj layout in ws: [t][b][512] f32, cols 0..127=k(-> k_hat after norm pass),
// 128..255=v, 256..383=q, 384..511=bx

#define T_STEPS 2048
#define NB 16
#define ND 128
#define KD 1024
#define PSTRIDE 512

typedef __attribute__((ext_vector_type(4))) float f32x4;
typedef __attribute__((ext_vector_type(8))) short short8v;

__device__ __forceinline__ unsigned short f2bf(float f) {
  union { float f; unsigned int u; } c; c.f = f;
  unsigned int u = c.u;
  unsigned int r = u + 0x7fffu + ((u >> 16) & 1u);   // round-to-nearest-even
  return (unsigned short)(r >> 16);
}

// ---------------------------------------------------------------------------
// Projection GEMM (unchanged from R1, ~56us): bf16 MFMA, 128x128 tile, BK=64,
// XOR-swizzled LDS.
// ---------------------------------------------------------------------------
__global__ __launch_bounds__(256) void proj_gemm(
    const float* __restrict__ X,
    const float* __restrict__ Wk, const float* __restrict__ Wv,
    const float* __restrict__ Wq, const float* __restrict__ Wb,
    float* __restrict__ C)
{
  __shared__ unsigned short As[128 * 64];
  __shared__ unsigned short Bs[128 * 64];
  const int tid = threadIdx.x;
  const int bm = blockIdx.x;           // 0..255
  const int bn = blockIdx.y;           // 0..3 -> which weight matrix
  const float* W = (bn == 0) ? Wk : ((bn == 1) ? Wv : ((bn == 2) ? Wq : Wb));
  const int lane = tid & 63;
  const int wave = tid >> 6;
  const int wr = wave >> 1, wc = wave & 1;   // wave computes 64x64 sub-tile

  f32x4 acc[4][4];
#pragma unroll
  for (int i = 0; i < 4; i++)
#pragma unroll
    for (int j = 0; j < 4; j++) acc[i][j] = (f32x4){0.f, 0.f, 0.f, 0.f};

  for (int k0 = 0; k0 < KD; k0 += 64) {
    __syncthreads();
#pragma unroll
    for (int c = 0; c < 4; c++) {
      const int g = tid + c * 256;     // 0..1023
      const int row = g >> 3;
      const int ch = g & 7;
      const int pos = ((ch ^ (row & 7)) * 8);
      {
        const float* ga = X + (size_t)(bm * 128 + row) * KD + k0 + ch * 8;
        float4 f0 = *(const float4*)(ga);
        float4 f1 = *(const float4*)(ga + 4);
        union { unsigned short u[8]; short8v v; } pk2;
        pk2.u[0] = f2bf(f0.x); pk2.u[1] = f2bf(f0.y);
        pk2.u[2] = f2bf(f0.z); pk2.u[3] = f2bf(f0.w);
        pk2.u[4] = f2bf(f1.x); pk2.u[5] = f2bf(f1.y);
        pk2.u[6] = f2bf(f1.z); pk2.u[7] = f2bf(f1.w);
        *reinterpret_cast<short8v*>(&As[row * 64 + pos]) = pk2.v;
      }
      {
        const float* gb = W + (size_t)row * KD + k0 + ch * 8;
        float4 f0 = *(const float4*)(gb);
        float4 f1 = *(const float4*)(gb + 4);
        union { unsigned short u[8]; short8v v; } pk2;
        pk2.u[0] = f2bf(f0.x); pk2.u[1] = f2bf(f0.y);
        pk2.u[2] = f2bf(f0.z); pk2.u[3] = f2bf(f0.w);
        pk2.u[4] = f2bf(f1.x); pk2.u[5] = f2bf(f1.y);
        pk2.u[6] = f2bf(f1.z); pk2.u[7] = f2bf(f1.w);
        *reinterpret_cast<short8v*>(&Bs[row * 64 + pos]) = pk2.v;
      }
    }
    __syncthreads();
#pragma unroll
    for (int kk = 0; kk < 2; kk++) {
      const int ch = kk * 4 + (lane >> 4);
      short8v a[4], b[4];
#pragma unroll
      for (int i = 0; i < 4; i++) {
        const int ar = wr * 64 + i * 16 + (lane & 15);
        a[i] = *reinterpret_cast<const short8v*>(&As[ar * 64 + ((ch ^ (ar & 7)) * 8)]);
        const int br = wc * 64 + i * 16 + (lane & 15);
        b[i] = *reinterpret_cast<const short8v*>(&Bs[br * 64 + ((ch ^ (br & 7)) * 8)]);
      }
#pragma unroll
      for (int i = 0; i < 4; i++)
#pragma unroll
        for (int j = 0; j < 4; j++)
          acc[i][j] = __builtin_amdgcn_mfma_f32_16x16x32_bf16(a[i], b[j], acc[i][j], 0, 0, 0);
    }
  }
#pragma unroll
  for (int i = 0; i < 4; i++)
#pragma unroll
    for (int j = 0; j < 4; j++)
#pragma unroll
      for (int r = 0; r < 4; r++) {
        const int row = bm * 128 + wr * 64 + i * 16 + (lane >> 4) * 4 + r;
        const int col = bn * 128 + wc * 64 + j * 16 + (lane & 15);
        C[(size_t)row * PSTRIDE + col] = acc[i][j][r];
      }
}

// ---------------------------------------------------------------------------
// k-normalization pre-pass: proj[row][0:128] <- k / (||k|| + eps).
// One wave per (t,b) row; lane holds 2 floats; 6-round full-wave reduce.
// Removes the ss/rnorm work (incl. one 3-shfl reduction) from every scan step.
// ---------------------------------------------------------------------------
__global__ __launch_bounds__(256) void norm_k(float* __restrict__ proj) {
  const int lane = threadIdx.x & 63;
  const int wid = (blockIdx.x * 256 + threadIdx.x) >> 6;   // 0..32767
  float* rowp = proj + (size_t)wid * PSTRIDE;
  float2 kv = *reinterpret_cast<float2*>(rowp + lane * 2);
  float ss = kv.x * kv.x + kv.y * kv.y;
  ss += __shfl_xor(ss, 1);
  ss += __shfl_xor(ss, 2);
  ss += __shfl_xor(ss, 4);
  ss += __shfl_xor(ss, 8);
  ss += __shfl_xor(ss, 16);
  ss += __shfl_xor(ss, 32);
  const float rn = 1.0f / (sqrtf(ss) + 1e-6f);
  kv.x *= rn; kv.y *= rn;
  *reinterpret_cast<float2*>(rowp + lane * 2) = kv;
}

// ---------------------------------------------------------------------------
// Sequential delta-rule scan, depth-4 register prefetch.
// One wave per (batch, 8-row group): 256 single-wave blocks, zero LDS/barriers.
// lane = rloc*8 + cblk: owns row (wv*8+rloc), cols [cblk*16, cblk*16+16).
// k is pre-normalized, so r = sum(S*kn), S += beta*(v-r)*kn directly.
// ---------------------------------------------------------------------------
__device__ __forceinline__ float sum8(float v) {
  v += __shfl_xor(v, 1);
  v += __shfl_xor(v, 2);
  v += __shfl_xor(v, 4);
  return v;
}

struct StepBuf {
  float4 kn[4]; float4 q[4]; float v, bx;
};

__device__ __forceinline__ void load_buf(const float* __restrict__ p, int cblk, int row,
                                         StepBuf& b) {
  const float4* p4 = reinterpret_cast<const float4*>(p);
#pragma unroll
  for (int j = 0; j < 4; j++) b.kn[j] = p4[cblk * 4 + j];
#pragma unroll
  for (int j = 0; j < 4; j++) b.q[j]  = p4[64 + cblk * 4 + j];
  b.v  = p[128 + row];
  b.bx = p[384 + row];
}

__device__ __forceinline__ float do_step(const StepBuf& b, float db, float bb,
                                         float S[16]) {
  float dka[4];
#pragma unroll
  for (int j = 0; j < 4; j++) {
    dka[j] = S[4 * j + 0] * b.kn[j].x + S[4 * j + 1] * b.kn[j].y +
             S[4 * j + 2] * b.kn[j].z + S[4 * j + 3] * b.kn[j].w;
  }
  const float r = sum8((dka[0] + dka[1]) + (dka[2] + dka[3]));   // retrieved[row]
  const float lg = fmaf(db, r, b.bx) + bb;
  const float beta = 1.0f / (1.0f + __expf(-lg));
  const float cr = beta * (b.v - r);
  float oda[4] = {0.f, 0.f, 0.f, 0.f};
#pragma unroll
  for (int j = 0; j < 4; j++) {
    S[4 * j + 0] = fmaf(cr, b.kn[j].x, S[4 * j + 0]); oda[j] = fmaf(S[4 * j + 0], b.q[j].x, oda[j]);
    S[4 * j + 1] = fmaf(cr, b.kn[j].y, S[4 * j + 1]); oda[j] = fmaf(S[4 * j + 1], b.q[j].y, oda[j]);
    S[4 * j + 2] = fmaf(cr, b.kn[j].z, S[4 * j + 2]); oda[j] = fmaf(S[4 * j + 2], b.q[j].z, oda[j]);
    S[4 * j + 3] = fmaf(cr, b.kn[j].w, S[4 * j + 3]); oda[j] = fmaf(S[4 * j + 3], b.q[j].w, oda[j]);
  }
  const float od = sum8((oda[0] + oda[1]) + (oda[2] + oda[3]));  // out = S@q
  const float sg = 1.0f / (1.0f + __expf(-od));
  return od * od * sg;                                           // out * silu(out)
}

__global__ __launch_bounds__(64) void scan_kernel(
    const float* __restrict__ proj, const float* __restrict__ S_in,
    const float* __restrict__ d_beta, const float* __restrict__ b_beta,
    float* __restrict__ out, float* __restrict__ S_out)
{
  const int lane = threadIdx.x & 63;
  // batch = blockIdx & 15: batches b and b+8 share XCD b%8 so each XCD's L2
  // holds only its 2 batches' proj slices.
  const int batch = blockIdx.x & 15;
  const int wv = blockIdx.x >> 4;      // 0..15 row-group
  const int rloc = lane >> 3;
  const int row = wv * 8 + rloc;
  const int cblk = lane & 7;
  const int c0 = cblk * 16;

  float S[16];
  {
    const float4* Sp4 = reinterpret_cast<const float4*>(
        S_in + ((size_t)batch * ND + row) * ND + c0);
#pragma unroll
    for (int j = 0; j < 4; j++) {
      float4 s4 = Sp4[j];
      S[4 * j + 0] = s4.x; S[4 * j + 1] = s4.y; S[4 * j + 2] = s4.z; S[4 * j + 3] = s4.w;
    }
  }
  const float db = d_beta[row];
  const float bb = b_beta[row];

  const float* pb = proj + (size_t)batch * PSTRIDE;
  const size_t sstep = (size_t)NB * PSTRIDE;
  float* outp = out + (size_t)batch * ND + row;
  const size_t ostep = (size_t)NB * ND;

  StepBuf A, B, C, D;
  load_buf(pb + 0 * sstep, cblk, row, A);
  load_buf(pb + 1 * sstep, cblk, row, B);
  load_buf(pb + 2 * sstep, cblk, row, C);
  load_buf(pb + 3 * sstep, cblk, row, D);

  for (int t = 0; t < T_STEPS; t += 4) {
    // slot A: consume A (step t), reload A <- t+4
    {
      float g = do_step(A, db, bb, S);
      if (cblk == 0) *outp = g;
      outp += ostep;
      const int tn = (t + 4 < T_STEPS) ? t + 4 : T_STEPS - 1;
      load_buf(pb + (size_t)tn * sstep, cblk, row, A);
    }
    // slot B: step t+1, reload B <- t+5
    {
      float g = do_step(B, db, bb, S);
      if (cblk == 0) *outp = g;
      outp += ostep;
      const int tn = (t + 5 < T_STEPS) ? t + 5 : T_STEPS - 1;
      load_buf(pb + (size_t)tn * sstep, cblk, row, B);
    }
    // slot C: step t+2, reload C <- t+6
    {
      float g = do_step(C, db, bb, S);
      if (cblk == 0) *outp = g;
      outp += ostep;
      const int tn = (t + 6 < T_STEPS) ? t + 6 : T_STEPS - 1;
      load_buf(pb + (size_t)tn * sstep, cblk, row, C);
    }
    // slot D: step t+3, reload D <- t+7
    {
      float g = do_step(D, db, bb, S);
      if (cblk == 0) *outp = g;
      outp += ostep;
      const int tn = (t + 7 < T_STEPS) ? t + 7 : T_STEPS - 1;
      load_buf(pb + (size_t)tn * sstep, cblk, row, D);
    }
  }
  {
    float4* So4 = reinterpret_cast<float4*>(
        S_out + ((size_t)batch * ND + row) * ND + c0);
#pragma unroll
    for (int j = 0; j < 4; j++) {
      float4 s4;
      s4.x = S[4 * j + 0]; s4.y = S[4 * j + 1]; s4.z = S[4 * j + 2]; s4.w = S[4 * j + 3];
      So4[j] = s4;
    }
  }
}

extern "C" void kernel_launch(void* const* d_in, const int* in_sizes, int n_in,
                              void* d_out, int out_size, void* d_ws, size_t ws_size,
                              hipStream_t stream) {
  const float* x  = (const float*)d_in[0];   // [2048][16][1024]
  const float* S0 = (const float*)d_in[1];   // [16][128][128]
  const float* Wk = (const float*)d_in[2];
  const float* Wv = (const float*)d_in[3];
  const float* Wq = (const float*)d_in[4];
  const float* Wb = (const float*)d_in[5];
  const float* db = (const float*)d_in[6];
  const float* bb = (const float*)d_in[7];
  float* out  = (float*)d_out;                           // [2048][16][128]
  float* Sout = out + (size_t)T_STEPS * NB * ND;         // [16][128][128]
  float* proj = (float*)d_ws;                            // [32768][512] = 64 MB

  dim3 ggrid(256, 4);
  proj_gemm<<<ggrid, 256, 0, stream>>>(x, Wk, Wv, Wq, Wb, proj);
  norm_k<<<8192, 256, 0, stream>>>(proj);
  scan_kernel<<<256, 64, 0, stream>>>(proj, S0, db, bb, out, Sout);
}